// Round 1
// baseline (2586.968 us; speedup 1.0000x reference)
//
#include <hip/hip_runtime.h>
#include <hip/hip_bf16.h>

#define D 512
#define T_ETYPES 8
#define NT_TYPES 4
#define K_MAIN 4096   // T_ETYPES * D
#define K_TOT 6144    // K_MAIN + NT_TYPES * D

typedef __attribute__((ext_vector_type(8))) short bf16x8;
typedef __attribute__((ext_vector_type(4))) float f32x4;

__device__ __forceinline__ unsigned short f2bf(float f) {
    union { float f; unsigned u; } u{f};
    unsigned r = u.u + 0x7FFF + ((u.u >> 16) & 1);   // RNE
    return (unsigned short)(r >> 16);
}

// ---- one-time weight prep: WbT[o][c] = bf16( c<4096 ? rel_W[c/512][c%512][o]
//                                                      : root_W[(c-4096)/512][(c-4096)%512][o] )
__global__ void convert_weights(const float* __restrict__ relW,
                                const float* __restrict__ rootW,
                                unsigned short* __restrict__ WbT) {
    __shared__ float tile[32][33];
    int c0 = blockIdx.x * 32;
    int o0 = blockIdx.y * 32;
    int tid = threadIdx.x;
#pragma unroll
    for (int it = 0; it < 4; ++it) {
        int idx = it * 256 + tid;
        int oc = idx & 31, cc = idx >> 5;
        int c = c0 + cc, o = o0 + oc;
        float v = (c < K_MAIN) ? relW[(size_t)c * D + o]
                               : rootW[(size_t)(c - K_MAIN) * D + o];
        tile[cc][oc] = v;
    }
    __syncthreads();
#pragma unroll
    for (int it = 0; it < 4; ++it) {
        int idx = it * 256 + tid;
        int cc = idx & 31, oc = idx >> 5;
        WbT[(size_t)(o0 + oc) * K_TOT + (c0 + cc)] = f2bf(tile[cc][oc]);
    }
}

// ---- edge aggregation: sums[dst][etype*512 + k] += x_src[src][k]; counts[dst*8+etype]++
__global__ void aggregate(const float* __restrict__ x_src,
                          const int* __restrict__ esrc,
                          const int* __restrict__ edst,
                          const int* __restrict__ etyp,
                          float* __restrict__ sums,
                          int* __restrict__ counts, int E) {
    int e = blockIdx.x * 4 + (threadIdx.x >> 6);
    if (e >= E) return;
    int lane = threadIdx.x & 63;
    int s = esrc[e], d = edst[e], t = etyp[e];
    const float4* src = reinterpret_cast<const float4*>(x_src + (size_t)s * D);
    float* dst = sums + (size_t)d * K_MAIN + t * D;
#pragma unroll
    for (int j = 0; j < 2; ++j) {
        float4 v = src[lane * 2 + j];
        int b = lane * 8 + j * 4;
        atomicAdd(dst + b + 0, v.x);
        atomicAdd(dst + b + 1, v.y);
        atomicAdd(dst + b + 2, v.z);
        atomicAdd(dst + b + 3, v.w);
    }
    if (lane == 0) atomicAdd(counts + d * T_ETYPES + t, 1);
}

__global__ void invcnt(const int* __restrict__ counts, float* __restrict__ inv, int n) {
    int i = blockIdx.x * 256 + threadIdx.x;
    if (i < n) inv[i] = 1.0f / fmaxf((float)counts[i], 1.0f);
}

// ---- GEMM: out[n][o] = sum_c A[n][c] * WbT[o][c]^T + root_b[tnt[n]][o]
//  A[n][c<4096]  = sums[n][c] * inv[n*8 + c/512]   (segment mean)
//  A[n][c>=4096] = (tnt[n]==g) ? x_target[n][k] : 0,  g=(c-4096)/512, k=(c-4096)%512
__global__ __launch_bounds__(256)
void rgcn_gemm(const float* __restrict__ sums, const float* __restrict__ inv,
               const unsigned short* __restrict__ WbT,
               const float* __restrict__ x_target, const int* __restrict__ tnt,
               const float* __restrict__ root_b, float* __restrict__ out, int M) {
    __shared__ unsigned short As[128 * 40];   // [row][k], stride 40 (pad kills bank conflicts)
    __shared__ unsigned short Bs[128 * 40];   // [col][k]
    const int tid = threadIdx.x;
    const int blockM = blockIdx.x * 128;
    const int blockN = blockIdx.y * 128;
    const int wid = tid >> 6, lane = tid & 63;
    const int wr = wid >> 1, wc = wid & 1;
    const int lr = lane & 15, lg = lane >> 4;

    f32x4 acc[4][4] = {};

    for (int k0 = 0; k0 < K_TOT; k0 += 32) {
        // ---- stage A (128 rows x 32 k, f32 -> scaled bf16)
#pragma unroll
        for (int it = 0; it < 4; ++it) {
            int task = it * 256 + tid;       // 0..1023
            int row = task >> 3, seg = task & 7;
            int gRow = blockM + row;
            float4 v = make_float4(0.f, 0.f, 0.f, 0.f);
            if (k0 < K_MAIN) {
                if (gRow < M) {
                    v = *reinterpret_cast<const float4*>(sums + (size_t)gRow * K_MAIN + k0 + seg * 4);
                    float sc = inv[gRow * T_ETYPES + (k0 >> 9)];
                    v.x *= sc; v.y *= sc; v.z *= sc; v.w *= sc;
                }
            } else {
                int g = (k0 - K_MAIN) >> 9;
                if (gRow < M && tnt[gRow] == g) {
                    int kk = ((k0 - K_MAIN) & 511) + seg * 4;
                    v = *reinterpret_cast<const float4*>(x_target + (size_t)gRow * D + kk);
                }
            }
            ushort4 w = make_ushort4(f2bf(v.x), f2bf(v.y), f2bf(v.z), f2bf(v.w));
            *reinterpret_cast<ushort4*>(&As[row * 40 + seg * 4]) = w;
        }
        // ---- stage B (128 cols x 32 k, bf16 copy)
#pragma unroll
        for (int it = 0; it < 2; ++it) {
            int task = it * 256 + tid;       // 0..511
            int col = task >> 2, seg = task & 3;
            *reinterpret_cast<uint4*>(&Bs[col * 40 + seg * 8]) =
                *reinterpret_cast<const uint4*>(WbT + (size_t)(blockN + col) * K_TOT + k0 + seg * 8);
        }
        __syncthreads();

        bf16x8 a_frag[4], b_frag[4];
#pragma unroll
        for (int mi = 0; mi < 4; ++mi)
            a_frag[mi] = *reinterpret_cast<const bf16x8*>(&As[(wr * 64 + mi * 16 + lr) * 40 + lg * 8]);
#pragma unroll
        for (int ni = 0; ni < 4; ++ni)
            b_frag[ni] = *reinterpret_cast<const bf16x8*>(&Bs[(wc * 64 + ni * 16 + lr) * 40 + lg * 8]);
#pragma unroll
        for (int mi = 0; mi < 4; ++mi)
#pragma unroll
            for (int ni = 0; ni < 4; ++ni)
                acc[mi][ni] = __builtin_amdgcn_mfma_f32_16x16x32_bf16(a_frag[mi], b_frag[ni], acc[mi][ni], 0, 0, 0);
        __syncthreads();
    }

    // ---- epilogue: + root bias, write f32
#pragma unroll
    for (int mi = 0; mi < 4; ++mi) {
#pragma unroll
        for (int r = 0; r < 4; ++r) {
            int row = blockM + wr * 64 + mi * 16 + lg * 4 + r;
            if (row < M) {
                int nt = tnt[row];
#pragma unroll
                for (int ni = 0; ni < 4; ++ni) {
                    int col = blockN + wc * 64 + ni * 16 + lr;
                    out[(size_t)row * D + col] = acc[mi][ni][r] + root_b[nt * D + col];
                }
            }
        }
    }
}

extern "C" void kernel_launch(void* const* d_in, const int* in_sizes, int n_in,
                              void* d_out, int out_size, void* d_ws, size_t ws_size,
                              hipStream_t stream) {
    const float* x_src    = (const float*)d_in[0];
    const float* x_target = (const float*)d_in[1];
    const float* relW     = (const float*)d_in[2];
    const float* rootW    = (const float*)d_in[3];
    const float* rootb    = (const float*)d_in[4];
    const int*   esrc     = (const int*)d_in[5];
    const int*   edst     = (const int*)d_in[6];
    const int*   etyp     = (const int*)d_in[7];
    const int*   tnt      = (const int*)d_in[8];
    float* out = (float*)d_out;

    const int E = in_sizes[5];
    const int M = in_sizes[8];          // n_tgt = 10000

    char* ws = (char*)d_ws;
    size_t sums_bytes   = (size_t)M * K_MAIN * sizeof(float);     // 163.84 MB
    size_t counts_bytes = (size_t)M * T_ETYPES * sizeof(int);     // 0.32 MB
    float*          sums   = (float*)ws;
    int*            counts = (int*)(ws + sums_bytes);
    float*          inv    = (float*)(ws + sums_bytes + counts_bytes);
    unsigned short* WbT    = (unsigned short*)(ws + sums_bytes + 2 * counts_bytes);

    hipMemsetAsync(sums, 0, sums_bytes + counts_bytes, stream);

    convert_weights<<<dim3(K_TOT / 32, D / 32), 256, 0, stream>>>(relW, rootW, WbT);
    aggregate<<<(E + 3) / 4, 256, 0, stream>>>(x_src, esrc, edst, etyp, sums, counts, E);
    invcnt<<<(M * T_ETYPES + 255) / 256, 256, 0, stream>>>(counts, inv, M * T_ETYPES);
    rgcn_gemm<<<dim3((M + 127) / 128, D / 128), 256, 0, stream>>>(
        sums, inv, WbT, x_target, tnt, rootb, out, M);
}

// Round 2
// 292.121 us; speedup vs baseline: 8.8558x; 8.8558x over previous
//
#include <hip/hip_runtime.h>
#include <hip/hip_bf16.h>

#define D 512
#define T_ETYPES 8
#define NT_TYPES 4
#define K_MAIN 4096   // T_ETYPES * D
#define K_TOT 6144    // K_MAIN + NT_TYPES * D

typedef __attribute__((ext_vector_type(8))) short bf16x8;
typedef __attribute__((ext_vector_type(4))) float f32x4;

__device__ __forceinline__ unsigned short f2bf(float f) {
    union { float f; unsigned u; } u{f};
    unsigned r = u.u + 0x7FFF + ((u.u >> 16) & 1);   // RNE
    return (unsigned short)(r >> 16);
}

// ---- one-time weight prep: WbT[o][c] = bf16( c<4096 ? rel_W[c/512][c%512][o]
//                                                      : root_W[(c-4096)/512][(c-4096)%512][o] )
__global__ void convert_weights(const float* __restrict__ relW,
                                const float* __restrict__ rootW,
                                unsigned short* __restrict__ WbT) {
    __shared__ float tile[32][33];
    int c0 = blockIdx.x * 32;
    int o0 = blockIdx.y * 32;
    int tid = threadIdx.x;
#pragma unroll
    for (int it = 0; it < 4; ++it) {
        int idx = it * 256 + tid;
        int oc = idx & 31, cc = idx >> 5;
        int c = c0 + cc, o = o0 + oc;
        float v = (c < K_MAIN) ? relW[(size_t)c * D + o]
                               : rootW[(size_t)(c - K_MAIN) * D + o];
        tile[cc][oc] = v;
    }
    __syncthreads();
#pragma unroll
    for (int it = 0; it < 4; ++it) {
        int idx = it * 256 + tid;
        int cc = idx & 31, oc = idx >> 5;
        WbT[(size_t)(o0 + oc) * K_TOT + (c0 + cc)] = f2bf(tile[cc][oc]);
    }
}

// ---- edge sort by seg = dst*8+etype: histogram -> scan -> scatter
__global__ void hist_kernel(const int* __restrict__ edst, const int* __restrict__ etyp,
                            int* __restrict__ counts, int E) {
    int e = blockIdx.x * 256 + threadIdx.x;
    if (e < E) atomicAdd(&counts[edst[e] * T_ETYPES + etyp[e]], 1);
}

__global__ void scan1(const int* __restrict__ counts, int* __restrict__ partial,
                      int* __restrict__ blockSums, int n) {
    __shared__ int sh[256];
    int tid = threadIdx.x, i = blockIdx.x * 256 + tid;
    int c = (i < n) ? counts[i] : 0;
    int val = c;
    sh[tid] = val; __syncthreads();
#pragma unroll
    for (int off = 1; off < 256; off <<= 1) {
        int add = (tid >= off) ? sh[tid - off] : 0;
        __syncthreads();
        val += add; sh[tid] = val;
        __syncthreads();
    }
    if (i < n) partial[i] = val - c;             // exclusive within block
    if (tid == 255) blockSums[blockIdx.x] = val; // block total
}

__global__ void scan2(int* __restrict__ blockSums, int nb) {
    __shared__ int sh[512];
    int tid = threadIdx.x;
    int c = (tid < nb) ? blockSums[tid] : 0;
    int val = c;
    sh[tid] = val; __syncthreads();
#pragma unroll
    for (int off = 1; off < 512; off <<= 1) {
        int add = (tid >= off) ? sh[tid - off] : 0;
        __syncthreads();
        val += add; sh[tid] = val;
        __syncthreads();
    }
    if (tid < nb) blockSums[tid] = val - c;      // exclusive block offsets
}

__global__ void scan3(const int* __restrict__ partial, const int* __restrict__ blockSums,
                      int* __restrict__ offsets, int* __restrict__ cursors, int n) {
    int i = blockIdx.x * 256 + threadIdx.x;
    if (i < n) {
        int v = partial[i] + blockSums[i >> 8];
        offsets[i] = v;
        cursors[i] = v;
    }
}

__global__ void scatter_kernel(const int* __restrict__ esrc, const int* __restrict__ edst,
                               const int* __restrict__ etyp, int* __restrict__ cursors,
                               int* __restrict__ perm, int E) {
    int e = blockIdx.x * 256 + threadIdx.x;
    if (e < E) {
        int seg = edst[e] * T_ETYPES + etyp[e];
        int pos = atomicAdd(&cursors[seg], 1);
        perm[pos] = esrc[e];
    }
}

// ---- segment mean, direct to bf16 A[dst][etype*512 + k]; one wave per segment
__global__ void segmean(const float* __restrict__ x_src, const int* __restrict__ perm,
                        const int* __restrict__ offsets, const int* __restrict__ counts,
                        unsigned short* __restrict__ A, int nseg) {
    int seg = blockIdx.x * 4 + (threadIdx.x >> 6);
    if (seg >= nseg) return;
    int lane = threadIdx.x & 63;
    int beg = offsets[seg], cnt = counts[seg];
    float4 a0 = make_float4(0.f, 0.f, 0.f, 0.f);
    float4 a1 = make_float4(0.f, 0.f, 0.f, 0.f);
    for (int i = 0; i < cnt; ++i) {
        int s = perm[beg + i];
        const float4* p = reinterpret_cast<const float4*>(x_src + (size_t)s * D);
        float4 v0 = p[lane * 2], v1 = p[lane * 2 + 1];
        a0.x += v0.x; a0.y += v0.y; a0.z += v0.z; a0.w += v0.w;
        a1.x += v1.x; a1.y += v1.y; a1.z += v1.z; a1.w += v1.w;
    }
    float sc = (cnt > 0) ? 1.0f / (float)cnt : 0.0f;
    uint4 u;
    u.x = (unsigned)f2bf(a0.x * sc) | ((unsigned)f2bf(a0.y * sc) << 16);
    u.y = (unsigned)f2bf(a0.z * sc) | ((unsigned)f2bf(a0.w * sc) << 16);
    u.z = (unsigned)f2bf(a1.x * sc) | ((unsigned)f2bf(a1.y * sc) << 16);
    u.w = (unsigned)f2bf(a1.z * sc) | ((unsigned)f2bf(a1.w * sc) << 16);
    int dst = seg >> 3, t = seg & 7;
    *reinterpret_cast<uint4*>(A + (size_t)dst * K_TOT + t * D + lane * 8) = u;
}

// ---- fill root columns: A[n][4096 + g*512 + k] = (tnt[n]==g) ? bf16(x_target[n][k]) : 0
__global__ void rootfill(const float* __restrict__ x_target, const int* __restrict__ tnt,
                         unsigned short* __restrict__ A, int M) {
    int n = blockIdx.x;
    int tid = threadIdx.x;          // 256 threads, each writes 8 bf16
    int nt = tnt[n];
    int col = tid * 8;              // 0..2047
    int g = col >> 9;
    uint4 u = make_uint4(0, 0, 0, 0);
    if (g == nt) {
        const float4* p = reinterpret_cast<const float4*>(x_target + (size_t)n * D + (col & 511));
        float4 v0 = p[0], v1 = p[1];
        u.x = (unsigned)f2bf(v0.x) | ((unsigned)f2bf(v0.y) << 16);
        u.y = (unsigned)f2bf(v0.z) | ((unsigned)f2bf(v0.w) << 16);
        u.z = (unsigned)f2bf(v1.x) | ((unsigned)f2bf(v1.y) << 16);
        u.w = (unsigned)f2bf(v1.z) | ((unsigned)f2bf(v1.w) << 16);
    }
    *reinterpret_cast<uint4*>(A + (size_t)n * K_TOT + K_MAIN + col) = u;
}

// ---- GEMM: out[n][o] = sum_c A[n][c] * WbT[o][c] + root_b[tnt[n]][o]
__global__ __launch_bounds__(256)
void rgcn_gemm(const unsigned short* __restrict__ A,
               const unsigned short* __restrict__ WbT,
               const int* __restrict__ tnt,
               const float* __restrict__ root_b, float* __restrict__ out, int M) {
    __shared__ unsigned short As[128 * 40];   // [row][k], stride 40 (pad kills bank conflicts)
    __shared__ unsigned short Bs[128 * 40];   // [col][k]
    const int tid = threadIdx.x;
    const int blockM = blockIdx.x * 128;
    const int blockN = blockIdx.y * 128;
    const int wid = tid >> 6, lane = tid & 63;
    const int wr = wid >> 1, wc = wid & 1;
    const int lr = lane & 15, lg = lane >> 4;

    f32x4 acc[4][4] = {};

    for (int k0 = 0; k0 < K_TOT; k0 += 32) {
        // ---- stage A (128 rows x 32 k, bf16 copy)
#pragma unroll
        for (int it = 0; it < 2; ++it) {
            int task = it * 256 + tid;       // 0..511
            int row = task >> 2, seg = task & 3;
            int gRow = blockM + row;
            uint4 v = make_uint4(0, 0, 0, 0);
            if (gRow < M)
                v = *reinterpret_cast<const uint4*>(A + (size_t)gRow * K_TOT + k0 + seg * 8);
            *reinterpret_cast<uint4*>(&As[row * 40 + seg * 8]) = v;
        }
        // ---- stage B (128 cols x 32 k, bf16 copy)
#pragma unroll
        for (int it = 0; it < 2; ++it) {
            int task = it * 256 + tid;       // 0..511
            int col = task >> 2, seg = task & 3;
            *reinterpret_cast<uint4*>(&Bs[col * 40 + seg * 8]) =
                *reinterpret_cast<const uint4*>(WbT + (size_t)(blockN + col) * K_TOT + k0 + seg * 8);
        }
        __syncthreads();

        bf16x8 a_frag[4], b_frag[4];
#pragma unroll
        for (int mi = 0; mi < 4; ++mi)
            a_frag[mi] = *reinterpret_cast<const bf16x8*>(&As[(wr * 64 + mi * 16 + lr) * 40 + lg * 8]);
#pragma unroll
        for (int ni = 0; ni < 4; ++ni)
            b_frag[ni] = *reinterpret_cast<const bf16x8*>(&Bs[(wc * 64 + ni * 16 + lr) * 40 + lg * 8]);
#pragma unroll
        for (int mi = 0; mi < 4; ++mi)
#pragma unroll
            for (int ni = 0; ni < 4; ++ni)
                acc[mi][ni] = __builtin_amdgcn_mfma_f32_16x16x32_bf16(a_frag[mi], b_frag[ni], acc[mi][ni], 0, 0, 0);
        __syncthreads();
    }

    // ---- epilogue: + root bias, write f32
#pragma unroll
    for (int mi = 0; mi < 4; ++mi) {
#pragma unroll
        for (int r = 0; r < 4; ++r) {
            int row = blockM + wr * 64 + mi * 16 + lg * 4 + r;
            if (row < M) {
                int nt = tnt[row];
#pragma unroll
                for (int ni = 0; ni < 4; ++ni) {
                    int col = blockN + wc * 64 + ni * 16 + lr;
                    out[(size_t)row * D + col] = acc[mi][ni][r] + root_b[nt * D + col];
                }
            }
        }
    }
}

extern "C" void kernel_launch(void* const* d_in, const int* in_sizes, int n_in,
                              void* d_out, int out_size, void* d_ws, size_t ws_size,
                              hipStream_t stream) {
    const float* x_src    = (const float*)d_in[0];
    const float* x_target = (const float*)d_in[1];
    const float* relW     = (const float*)d_in[2];
    const float* rootW    = (const float*)d_in[3];
    const float* rootb    = (const float*)d_in[4];
    const int*   esrc     = (const int*)d_in[5];
    const int*   edst     = (const int*)d_in[6];
    const int*   etyp     = (const int*)d_in[7];
    const int*   tnt      = (const int*)d_in[8];
    float* out = (float*)d_out;

    const int E = in_sizes[5];
    const int M = in_sizes[8];          // n_tgt = 10000
    const int NSEG = M * T_ETYPES;      // 80000
    const int NB = (NSEG + 255) / 256;  // 313

    char* ws = (char*)d_ws;
    size_t off = 0;
    unsigned short* Abf = (unsigned short*)(ws + off); off += (size_t)M * K_TOT * 2;     // 122.88 MB
    unsigned short* WbT = (unsigned short*)(ws + off); off += (size_t)D * K_TOT * 2;     // 6.29 MB
    int* counts    = (int*)(ws + off); off += (size_t)NSEG * 4;
    int* partial   = (int*)(ws + off); off += (size_t)NSEG * 4;
    int* offsets   = (int*)(ws + off); off += (size_t)NSEG * 4;
    int* cursors   = (int*)(ws + off); off += (size_t)NSEG * 4;
    int* blockSums = (int*)(ws + off); off += 512 * 4;
    int* perm      = (int*)(ws + off); off += (size_t)E * 4;

    hipMemsetAsync(counts, 0, (size_t)NSEG * 4, stream);

    convert_weights<<<dim3(K_TOT / 32, D / 32), 256, 0, stream>>>(relW, rootW, WbT);
    hist_kernel<<<(E + 255) / 256, 256, 0, stream>>>(edst, etyp, counts, E);
    scan1<<<NB, 256, 0, stream>>>(counts, partial, blockSums, NSEG);
    scan2<<<1, 512, 0, stream>>>(blockSums, NB);
    scan3<<<NB, 256, 0, stream>>>(partial, blockSums, offsets, cursors, NSEG);
    scatter_kernel<<<(E + 255) / 256, 256, 0, stream>>>(esrc, edst, etyp, cursors, perm, E);
    segmean<<<(NSEG + 3) / 4, 256, 0, stream>>>(x_src, perm, offsets, counts, Abf, NSEG);
    rootfill<<<M, 256, 0, stream>>>(x_target, tnt, Abf, M);
    rgcn_gemm<<<dim3((M + 127) / 128, D / 128), 256, 0, stream>>>(
        Abf, WbT, tnt, rootb, out, M);
}

// Round 3
// 220.265 us; speedup vs baseline: 11.7448x; 1.3262x over previous
//
#include <hip/hip_runtime.h>
#include <hip/hip_bf16.h>

#define D 512
#define T_ETYPES 8
#define NT_TYPES 4
#define K_MAIN 4096   // T_ETYPES * D
#define K_TOT 6144    // K_MAIN + NT_TYPES * D
#define SPLITS 3
#define KSPLIT 2048   // K_TOT / SPLITS

typedef __attribute__((ext_vector_type(8))) short bf16x8;
typedef __attribute__((ext_vector_type(4))) float f32x4;

__device__ __forceinline__ unsigned short f2bf(float f) {
    union { float f; unsigned u; } u{f};
    unsigned r = u.u + 0x7FFF + ((u.u >> 16) & 1);   // RNE
    return (unsigned short)(r >> 16);
}
__device__ __forceinline__ float bf2f(unsigned short h) {
    union { unsigned u; float f; } v{(unsigned)h << 16};
    return v.f;
}

// async global->LDS, 16B per lane (LDS dest must be wave-uniform base + lane*16)
__device__ __forceinline__ void gl16(const unsigned short* g, unsigned short* l) {
    __builtin_amdgcn_global_load_lds(
        (const __attribute__((address_space(1))) unsigned int*)g,
        (__attribute__((address_space(3))) unsigned int*)l,
        16, 0, 0);
}

// ---- one-time weight prep: WbT[o][c] = bf16( c<4096 ? rel_W[c/512][c%512][o]
//                                                      : root_W[(c-4096)/512][(c-4096)%512][o] )
__global__ void convert_weights(const float* __restrict__ relW,
                                const float* __restrict__ rootW,
                                unsigned short* __restrict__ WbT) {
    __shared__ float tile[32][33];
    int c0 = blockIdx.x * 32;
    int o0 = blockIdx.y * 32;
    int tid = threadIdx.x;
#pragma unroll
    for (int it = 0; it < 4; ++it) {
        int idx = it * 256 + tid;
        int oc = idx & 31, cc = idx >> 5;
        int c = c0 + cc, o = o0 + oc;
        float v = (c < K_MAIN) ? relW[(size_t)c * D + o]
                               : rootW[(size_t)(c - K_MAIN) * D + o];
        tile[cc][oc] = v;
    }
    __syncthreads();
#pragma unroll
    for (int it = 0; it < 4; ++it) {
        int idx = it * 256 + tid;
        int cc = idx & 31, oc = idx >> 5;
        WbT[(size_t)(o0 + oc) * K_TOT + (c0 + cc)] = f2bf(tile[cc][oc]);
    }
}

// ---- edge sort by seg = dst*8+etype: histogram -> scan -> scatter
__global__ void hist_kernel(const int* __restrict__ edst, const int* __restrict__ etyp,
                            int* __restrict__ counts, int E) {
    int e = blockIdx.x * 256 + threadIdx.x;
    if (e < E) atomicAdd(&counts[edst[e] * T_ETYPES + etyp[e]], 1);
}

__global__ void scan1(const int* __restrict__ counts, int* __restrict__ partial,
                      int* __restrict__ blockSums, int n) {
    __shared__ int sh[256];
    int tid = threadIdx.x, i = blockIdx.x * 256 + tid;
    int c = (i < n) ? counts[i] : 0;
    int val = c;
    sh[tid] = val; __syncthreads();
#pragma unroll
    for (int off = 1; off < 256; off <<= 1) {
        int add = (tid >= off) ? sh[tid - off] : 0;
        __syncthreads();
        val += add; sh[tid] = val;
        __syncthreads();
    }
    if (i < n) partial[i] = val - c;             // exclusive within block
    if (tid == 255) blockSums[blockIdx.x] = val; // block total
}

__global__ void scan2(int* __restrict__ blockSums, int nb) {
    __shared__ int sh[512];
    int tid = threadIdx.x;
    int c = (tid < nb) ? blockSums[tid] : 0;
    int val = c;
    sh[tid] = val; __syncthreads();
#pragma unroll
    for (int off = 1; off < 512; off <<= 1) {
        int add = (tid >= off) ? sh[tid - off] : 0;
        __syncthreads();
        val += add; sh[tid] = val;
        __syncthreads();
    }
    if (tid < nb) blockSums[tid] = val - c;      // exclusive block offsets
}

__global__ void scan3(const int* __restrict__ partial, const int* __restrict__ blockSums,
                      int* __restrict__ offsets, int* __restrict__ cursors, int n) {
    int i = blockIdx.x * 256 + threadIdx.x;
    if (i < n) {
        int v = partial[i] + blockSums[i >> 8];
        offsets[i] = v;
        cursors[i] = v;
    }
}

__global__ void scatter_kernel(const int* __restrict__ esrc, const int* __restrict__ edst,
                               const int* __restrict__ etyp, int* __restrict__ cursors,
                               int* __restrict__ perm, int E) {
    int e = blockIdx.x * 256 + threadIdx.x;
    if (e < E) {
        int seg = edst[e] * T_ETYPES + etyp[e];
        int pos = atomicAdd(&cursors[seg], 1);
        perm[pos] = esrc[e];
    }
}

// ---- segment mean, direct to bf16 A[dst][etype*512 + k]; one wave per segment
__global__ void segmean(const float* __restrict__ x_src, const int* __restrict__ perm,
                        const int* __restrict__ offsets, const int* __restrict__ counts,
                        unsigned short* __restrict__ A, int nseg) {
    int seg = blockIdx.x * 4 + (threadIdx.x >> 6);
    if (seg >= nseg) return;
    int lane = threadIdx.x & 63;
    int beg = offsets[seg], cnt = counts[seg];
    float4 a0 = make_float4(0.f, 0.f, 0.f, 0.f);
    float4 a1 = make_float4(0.f, 0.f, 0.f, 0.f);
    for (int i = 0; i < cnt; ++i) {
        int s = perm[beg + i];
        const float4* p = reinterpret_cast<const float4*>(x_src + (size_t)s * D);
        float4 v0 = p[lane * 2], v1 = p[lane * 2 + 1];
        a0.x += v0.x; a0.y += v0.y; a0.z += v0.z; a0.w += v0.w;
        a1.x += v1.x; a1.y += v1.y; a1.z += v1.z; a1.w += v1.w;
    }
    float sc = (cnt > 0) ? 1.0f / (float)cnt : 0.0f;
    uint4 u;
    u.x = (unsigned)f2bf(a0.x * sc) | ((unsigned)f2bf(a0.y * sc) << 16);
    u.y = (unsigned)f2bf(a0.z * sc) | ((unsigned)f2bf(a0.w * sc) << 16);
    u.z = (unsigned)f2bf(a1.x * sc) | ((unsigned)f2bf(a1.y * sc) << 16);
    u.w = (unsigned)f2bf(a1.z * sc) | ((unsigned)f2bf(a1.w * sc) << 16);
    int dst = seg >> 3, t = seg & 7;
    *reinterpret_cast<uint4*>(A + (size_t)dst * K_TOT + t * D + lane * 8) = u;
}

// ---- fill root columns: A[n][4096 + g*512 + k] = (tnt[n]==g) ? bf16(x_target[n][k]) : 0
__global__ void rootfill(const float* __restrict__ x_target, const int* __restrict__ tnt,
                         unsigned short* __restrict__ A, int M) {
    int n = blockIdx.x;
    int tid = threadIdx.x;          // 256 threads, each writes 8 bf16
    int nt = tnt[n];
    int col = tid * 8;              // 0..2047
    int g = col >> 9;
    uint4 u = make_uint4(0, 0, 0, 0);
    if (g == nt) {
        const float4* p = reinterpret_cast<const float4*>(x_target + (size_t)n * D + (col & 511));
        float4 v0 = p[0], v1 = p[1];
        u.x = (unsigned)f2bf(v0.x) | ((unsigned)f2bf(v0.y) << 16);
        u.y = (unsigned)f2bf(v0.z) | ((unsigned)f2bf(v0.w) << 16);
        u.z = (unsigned)f2bf(v1.x) | ((unsigned)f2bf(v1.y) << 16);
        u.w = (unsigned)f2bf(v1.z) | ((unsigned)f2bf(v1.w) << 16);
    }
    *reinterpret_cast<uint4*>(A + (size_t)n * K_TOT + K_MAIN + col) = u;
}

// ---- split-K GEMM: pbuf[z][n][o] = sum_{c in split z} A[n][c] * WbT[o][c]
// m97 structure: global_load_lds width-16 staging, linear LDS [128][32], 2-barrier loop.
__global__ __launch_bounds__(256, 4)
void rgcn_gemm_sk(const unsigned short* __restrict__ A,
                  const unsigned short* __restrict__ WbT,
                  unsigned short* __restrict__ pbuf, int M) {
    __shared__ unsigned short As[128 * 32];
    __shared__ unsigned short Bs[128 * 32];
    const int tid = threadIdx.x;
    const int blockM = blockIdx.x * 128;
    const int blockN = blockIdx.y * 128;
    const int kBase = blockIdx.z * KSPLIT;
    const int wid = tid >> 6, lane = tid & 63;
    const int wr = wid >> 1, wc = wid & 1;
    const int lr = lane & 15, lg = lane >> 4;

    f32x4 acc[4][4] = {};

    // staging chunk ids: chunk c (0..511) -> row c>>2, k-seg c&3; LDS bytes [c*16, c*16+16)
    const int c0 = tid, c1 = 256 + tid;
    const unsigned short* Abase = A + (size_t)blockM * K_TOT + kBase;
    const unsigned short* Bbase = WbT + (size_t)blockN * K_TOT + kBase;
    // NOTE: rows >= M read garbage from elsewhere in ws (mapped, deterministic);
    // their acc is never stored.

    for (int k0 = 0; k0 < KSPLIT; k0 += 32) {
        gl16(Abase + (size_t)(c0 >> 2) * K_TOT + k0 + (c0 & 3) * 8, &As[c0 * 8]);
        gl16(Abase + (size_t)(c1 >> 2) * K_TOT + k0 + (c1 & 3) * 8, &As[c1 * 8]);
        gl16(Bbase + (size_t)(c0 >> 2) * K_TOT + k0 + (c0 & 3) * 8, &Bs[c0 * 8]);
        gl16(Bbase + (size_t)(c1 >> 2) * K_TOT + k0 + (c1 & 3) * 8, &Bs[c1 * 8]);
        __syncthreads();

        bf16x8 a_frag[4], b_frag[4];
#pragma unroll
        for (int mi = 0; mi < 4; ++mi)
            a_frag[mi] = *reinterpret_cast<const bf16x8*>(&As[(wr * 64 + mi * 16 + lr) * 32 + lg * 8]);
#pragma unroll
        for (int ni = 0; ni < 4; ++ni)
            b_frag[ni] = *reinterpret_cast<const bf16x8*>(&Bs[(wc * 64 + ni * 16 + lr) * 32 + lg * 8]);
#pragma unroll
        for (int mi = 0; mi < 4; ++mi)
#pragma unroll
            for (int ni = 0; ni < 4; ++ni)
                acc[mi][ni] = __builtin_amdgcn_mfma_f32_16x16x32_bf16(a_frag[mi], b_frag[ni], acc[mi][ni], 0, 0, 0);
        __syncthreads();
    }

    // epilogue: bf16 partial per split
#pragma unroll
    for (int mi = 0; mi < 4; ++mi) {
#pragma unroll
        for (int r = 0; r < 4; ++r) {
            int row = blockM + wr * 64 + mi * 16 + lg * 4 + r;
            if (row < M) {
#pragma unroll
                for (int ni = 0; ni < 4; ++ni) {
                    int col = blockN + wc * 64 + ni * 16 + lr;
                    pbuf[((size_t)blockIdx.z * M + row) * D + col] = f2bf(acc[mi][ni][r]);
                }
            }
        }
    }
}

// ---- reduce splits + per-type bias -> f32 out
__global__ void reduce_bias(const unsigned short* __restrict__ pbuf,
                            const int* __restrict__ tnt, const float* __restrict__ root_b,
                            float* __restrict__ out, int M) {
    int idx = blockIdx.x * 256 + threadIdx.x;   // one per 8 outputs
    if (idx >= M * (D / 8)) return;
    int row = idx >> 6;            // D/8 = 64
    int col = (idx & 63) * 8;
    float s[8] = {0.f, 0.f, 0.f, 0.f, 0.f, 0.f, 0.f, 0.f};
#pragma unroll
    for (int sp = 0; sp < SPLITS; ++sp) {
        uint4 v = *reinterpret_cast<const uint4*>(pbuf + ((size_t)sp * M + row) * D + col);
        unsigned u[4] = {v.x, v.y, v.z, v.w};
#pragma unroll
        for (int j = 0; j < 4; ++j) {
            s[2 * j]     += bf2f((unsigned short)(u[j] & 0xFFFF));
            s[2 * j + 1] += bf2f((unsigned short)(u[j] >> 16));
        }
    }
    const float* b = root_b + (size_t)tnt[row] * D + col;
    float4 o0, o1;
    o0.x = s[0] + b[0]; o0.y = s[1] + b[1]; o0.z = s[2] + b[2]; o0.w = s[3] + b[3];
    o1.x = s[4] + b[4]; o1.y = s[5] + b[5]; o1.z = s[6] + b[6]; o1.w = s[7] + b[7];
    float* o = out + (size_t)row * D + col;
    *reinterpret_cast<float4*>(o) = o0;
    *reinterpret_cast<float4*>(o + 4) = o1;
}

extern "C" void kernel_launch(void* const* d_in, const int* in_sizes, int n_in,
                              void* d_out, int out_size, void* d_ws, size_t ws_size,
                              hipStream_t stream) {
    const float* x_src    = (const float*)d_in[0];
    const float* x_target = (const float*)d_in[1];
    const float* relW     = (const float*)d_in[2];
    const float* rootW    = (const float*)d_in[3];
    const float* rootb    = (const float*)d_in[4];
    const int*   esrc     = (const int*)d_in[5];
    const int*   edst     = (const int*)d_in[6];
    const int*   etyp     = (const int*)d_in[7];
    const int*   tnt      = (const int*)d_in[8];
    float* out = (float*)d_out;

    const int E = in_sizes[5];
    const int M = in_sizes[8];          // n_tgt = 10000
    const int NSEG = M * T_ETYPES;      // 80000
    const int NB = (NSEG + 255) / 256;  // 313

    char* ws = (char*)d_ws;
    size_t off = 0;
    unsigned short* Abf = (unsigned short*)(ws + off); off += (size_t)M * K_TOT * 2;       // 122.88 MB
    unsigned short* WbT = (unsigned short*)(ws + off); off += (size_t)D * K_TOT * 2;       // 6.29 MB
    unsigned short* pb  = (unsigned short*)(ws + off); off += (size_t)SPLITS * M * D * 2;  // 30.72 MB
    int* counts    = (int*)(ws + off); off += (size_t)NSEG * 4;
    int* partial   = (int*)(ws + off); off += (size_t)NSEG * 4;
    int* offsets   = (int*)(ws + off); off += (size_t)NSEG * 4;
    int* cursors   = (int*)(ws + off); off += (size_t)NSEG * 4;
    int* blockSums = (int*)(ws + off); off += 512 * 4;
    int* perm      = (int*)(ws + off); off += (size_t)E * 4;

    hipMemsetAsync(counts, 0, (size_t)NSEG * 4, stream);

    convert_weights<<<dim3(K_TOT / 32, D / 32), 256, 0, stream>>>(relW, rootW, WbT);
    hist_kernel<<<(E + 255) / 256, 256, 0, stream>>>(edst, etyp, counts, E);
    scan1<<<NB, 256, 0, stream>>>(counts, partial, blockSums, NSEG);
    scan2<<<1, 512, 0, stream>>>(blockSums, NB);
    scan3<<<NB, 256, 0, stream>>>(partial, blockSums, offsets, cursors, NSEG);
    scatter_kernel<<<(E + 255) / 256, 256, 0, stream>>>(esrc, edst, etyp, cursors, perm, E);
    segmean<<<(NSEG + 3) / 4, 256, 0, stream>>>(x_src, perm, offsets, counts, Abf, NSEG);
    rootfill<<<M, 256, 0, stream>>>(x_target, tnt, Abf, M);
    rgcn_gemm_sk<<<dim3((M + 127) / 128, D / 128, SPLITS), 256, 0, stream>>>(
        Abf, WbT, pb, M);
    reduce_bias<<<(M * (D / 8) + 255) / 256, 256, 0, stream>>>(pb, tnt, rootb, out, M);
}

// Round 4
// 206.804 us; speedup vs baseline: 12.5093x; 1.0651x over previous
//
#include <hip/hip_runtime.h>
#include <hip/hip_bf16.h>

#define D 512
#define T_ETYPES 8
#define NT_TYPES 4
#define K_MAIN 4096   // T_ETYPES * D
#define K_TOT 6144    // K_MAIN + NT_TYPES * D
#define SPLITS 4
#define KSPLIT 1536   // K_TOT / SPLITS

typedef __attribute__((ext_vector_type(8))) short bf16x8;
typedef __attribute__((ext_vector_type(4))) float f32x4;

__device__ __forceinline__ unsigned short f2bf(float f) {
    union { float f; unsigned u; } u{f};
    unsigned r = u.u + 0x7FFF + ((u.u >> 16) & 1);   // RNE
    return (unsigned short)(r >> 16);
}
__device__ __forceinline__ float bf2f(unsigned short h) {
    union { unsigned u; float f; } v{(unsigned)h << 16};
    return v.f;
}

// async global->LDS, 16B per lane (LDS dest must be wave-uniform base + lane*16)
__device__ __forceinline__ void gl16(const unsigned short* g, unsigned short* l) {
    __builtin_amdgcn_global_load_lds(
        (const __attribute__((address_space(1))) unsigned int*)g,
        (__attribute__((address_space(3))) unsigned int*)l,
        16, 0, 0);
}

// ---- one-time weight prep: WbT[o][c] = bf16( c<4096 ? rel_W[c/512][c%512][o]
//                                                      : root_W[(c-4096)/512][(c-4096)%512][o] )
__global__ void convert_weights(const float* __restrict__ relW,
                                const float* __restrict__ rootW,
                                unsigned short* __restrict__ WbT) {
    __shared__ float tile[32][33];
    int c0 = blockIdx.x * 32;
    int o0 = blockIdx.y * 32;
    int tid = threadIdx.x;
#pragma unroll
    for (int it = 0; it < 4; ++it) {
        int idx = it * 256 + tid;
        int oc = idx & 31, cc = idx >> 5;
        int c = c0 + cc, o = o0 + oc;
        float v = (c < K_MAIN) ? relW[(size_t)c * D + o]
                               : rootW[(size_t)(c - K_MAIN) * D + o];
        tile[cc][oc] = v;
    }
    __syncthreads();
#pragma unroll
    for (int it = 0; it < 4; ++it) {
        int idx = it * 256 + tid;
        int cc = idx & 31, oc = idx >> 5;
        WbT[(size_t)(o0 + oc) * K_TOT + (c0 + cc)] = f2bf(tile[cc][oc]);
    }
}

// ---- edge sort by seg = dst*8+etype: histogram -> scan -> scatter
__global__ void hist_kernel(const int* __restrict__ edst, const int* __restrict__ etyp,
                            int* __restrict__ counts, int E) {
    int e = blockIdx.x * 256 + threadIdx.x;
    if (e < E) atomicAdd(&counts[edst[e] * T_ETYPES + etyp[e]], 1);
}

__global__ void scan1(const int* __restrict__ counts, int* __restrict__ partial,
                      int* __restrict__ blockSums, int n) {
    __shared__ int sh[256];
    int tid = threadIdx.x, i = blockIdx.x * 256 + tid;
    int c = (i < n) ? counts[i] : 0;
    int val = c;
    sh[tid] = val; __syncthreads();
#pragma unroll
    for (int off = 1; off < 256; off <<= 1) {
        int add = (tid >= off) ? sh[tid - off] : 0;
        __syncthreads();
        val += add; sh[tid] = val;
        __syncthreads();
    }
    if (i < n) partial[i] = val - c;             // exclusive within block
    if (tid == 255) blockSums[blockIdx.x] = val; // block total
}

__global__ void scan2(int* __restrict__ blockSums, int nb) {
    __shared__ int sh[512];
    int tid = threadIdx.x;
    int c = (tid < nb) ? blockSums[tid] : 0;
    int val = c;
    sh[tid] = val; __syncthreads();
#pragma unroll
    for (int off = 1; off < 512; off <<= 1) {
        int add = (tid >= off) ? sh[tid - off] : 0;
        __syncthreads();
        val += add; sh[tid] = val;
        __syncthreads();
    }
    if (tid < nb) blockSums[tid] = val - c;      // exclusive block offsets
}

__global__ void scan3(const int* __restrict__ partial, const int* __restrict__ blockSums,
                      int* __restrict__ offsets, int* __restrict__ cursors, int n) {
    int i = blockIdx.x * 256 + threadIdx.x;
    if (i < n) {
        int v = partial[i] + blockSums[i >> 8];
        offsets[i] = v;
        cursors[i] = v;
    }
}

__global__ void scatter_kernel(const int* __restrict__ esrc, const int* __restrict__ edst,
                               const int* __restrict__ etyp, int* __restrict__ cursors,
                               int* __restrict__ perm, int E) {
    int e = blockIdx.x * 256 + threadIdx.x;
    if (e < E) {
        int seg = edst[e] * T_ETYPES + etyp[e];
        int pos = atomicAdd(&cursors[seg], 1);
        perm[pos] = esrc[e];
    }
}

// ---- segment mean, direct to bf16 A[dst][etype*512 + k]; one wave per segment
__global__ void segmean(const float* __restrict__ x_src, const int* __restrict__ perm,
                        const int* __restrict__ offsets, const int* __restrict__ counts,
                        unsigned short* __restrict__ A, int nseg) {
    int seg = blockIdx.x * 4 + (threadIdx.x >> 6);
    if (seg >= nseg) return;
    int lane = threadIdx.x & 63;
    int beg = offsets[seg], cnt = counts[seg];
    float4 a0 = make_float4(0.f, 0.f, 0.f, 0.f);
    float4 a1 = make_float4(0.f, 0.f, 0.f, 0.f);
    for (int i = 0; i < cnt; ++i) {
        int s = perm[beg + i];
        const float4* p = reinterpret_cast<const float4*>(x_src + (size_t)s * D);
        float4 v0 = p[lane * 2], v1 = p[lane * 2 + 1];
        a0.x += v0.x; a0.y += v0.y; a0.z += v0.z; a0.w += v0.w;
        a1.x += v1.x; a1.y += v1.y; a1.z += v1.z; a1.w += v1.w;
    }
    float sc = (cnt > 0) ? 1.0f / (float)cnt : 0.0f;
    uint4 u;
    u.x = (unsigned)f2bf(a0.x * sc) | ((unsigned)f2bf(a0.y * sc) << 16);
    u.y = (unsigned)f2bf(a0.z * sc) | ((unsigned)f2bf(a0.w * sc) << 16);
    u.z = (unsigned)f2bf(a1.x * sc) | ((unsigned)f2bf(a1.y * sc) << 16);
    u.w = (unsigned)f2bf(a1.z * sc) | ((unsigned)f2bf(a1.w * sc) << 16);
    int dst = seg >> 3, t = seg & 7;
    *reinterpret_cast<uint4*>(A + (size_t)dst * K_TOT + t * D + lane * 8) = u;
}

// ---- fill root columns: A[n][4096 + g*512 + k] = (tnt[n]==g) ? bf16(x_target[n][k]) : 0
__global__ void rootfill(const float* __restrict__ x_target, const int* __restrict__ tnt,
                         unsigned short* __restrict__ A, int M) {
    int n = blockIdx.x;
    int tid = threadIdx.x;          // 256 threads, each writes 8 bf16
    int nt = tnt[n];
    int col = tid * 8;              // 0..2047
    int g = col >> 9;
    uint4 u = make_uint4(0, 0, 0, 0);
    if (g == nt) {
        const float4* p = reinterpret_cast<const float4*>(x_target + (size_t)n * D + (col & 511));
        float4 v0 = p[0], v1 = p[1];
        u.x = (unsigned)f2bf(v0.x) | ((unsigned)f2bf(v0.y) << 16);
        u.y = (unsigned)f2bf(v0.z) | ((unsigned)f2bf(v0.w) << 16);
        u.z = (unsigned)f2bf(v1.x) | ((unsigned)f2bf(v1.y) << 16);
        u.w = (unsigned)f2bf(v1.z) | ((unsigned)f2bf(v1.w) << 16);
    }
    *reinterpret_cast<uint4*>(A + (size_t)n * K_TOT + K_MAIN + col) = u;
}

// ---- split-K GEMM: pbuf[z][n][o] = sum_{c in split z} A[n][c] * WbT[o][c]
// 1D grid, XCD-chunk swizzle, A-panel-major logical order: l = ((z*MB + m)*4 + n).
// The 4 N-blocks sharing one (m,z) A-panel slice land on the same XCD's L2.
__global__ __launch_bounds__(256, 4)
void rgcn_gemm_sk(const unsigned short* __restrict__ A,
                  const unsigned short* __restrict__ WbT,
                  unsigned short* __restrict__ pbuf, int M, int MB) {
    __shared__ unsigned short As[128 * 32];
    __shared__ unsigned short Bs[128 * 32];
    const int tid = threadIdx.x;

    // swizzled logical id
    int d = blockIdx.x;
    int l = d;
    if ((gridDim.x & 7) == 0) {
        int cpx = gridDim.x >> 3;
        l = (d & 7) * cpx + (d >> 3);
    }
    const int nIdx = l & 3;
    const int mz = l >> 2;
    const int mIdx = mz % MB;
    const int zIdx = mz / MB;

    const int blockM = mIdx * 128;
    const int blockN = nIdx * 128;
    const int kBase = zIdx * KSPLIT;
    const int wid = tid >> 6, lane = tid & 63;
    const int wr = wid >> 1, wc = wid & 1;
    const int lr = lane & 15, lg = lane >> 4;

    f32x4 acc[4][4] = {};

    // staging chunk ids: chunk c (0..511) -> row c>>2, k-seg c&3; LDS bytes [c*16, c*16+16)
    const int c0 = tid, c1 = 256 + tid;
    const unsigned short* Abase = A + (size_t)blockM * K_TOT + kBase;
    const unsigned short* Bbase = WbT + (size_t)blockN * K_TOT + kBase;
    // NOTE: rows >= M read garbage from elsewhere in ws (mapped, deterministic);
    // their acc is never stored.

    for (int k0 = 0; k0 < KSPLIT; k0 += 32) {
        gl16(Abase + (size_t)(c0 >> 2) * K_TOT + k0 + (c0 & 3) * 8, &As[c0 * 8]);
        gl16(Abase + (size_t)(c1 >> 2) * K_TOT + k0 + (c1 & 3) * 8, &As[c1 * 8]);
        gl16(Bbase + (size_t)(c0 >> 2) * K_TOT + k0 + (c0 & 3) * 8, &Bs[c0 * 8]);
        gl16(Bbase + (size_t)(c1 >> 2) * K_TOT + k0 + (c1 & 3) * 8, &Bs[c1 * 8]);
        __syncthreads();

        bf16x8 a_frag[4], b_frag[4];
#pragma unroll
        for (int mi = 0; mi < 4; ++mi)
            a_frag[mi] = *reinterpret_cast<const bf16x8*>(&As[(wr * 64 + mi * 16 + lr) * 32 + lg * 8]);
#pragma unroll
        for (int ni = 0; ni < 4; ++ni)
            b_frag[ni] = *reinterpret_cast<const bf16x8*>(&Bs[(wc * 64 + ni * 16 + lr) * 32 + lg * 8]);
#pragma unroll
        for (int mi = 0; mi < 4; ++mi)
#pragma unroll
            for (int ni = 0; ni < 4; ++ni)
                acc[mi][ni] = __builtin_amdgcn_mfma_f32_16x16x32_bf16(a_frag[mi], b_frag[ni], acc[mi][ni], 0, 0, 0);
        __syncthreads();
    }

    // epilogue: bf16 partial per split
#pragma unroll
    for (int mi = 0; mi < 4; ++mi) {
#pragma unroll
        for (int r = 0; r < 4; ++r) {
            int row = blockM + wr * 64 + mi * 16 + lg * 4 + r;
            if (row < M) {
#pragma unroll
                for (int ni = 0; ni < 4; ++ni) {
                    int col = blockN + wc * 64 + ni * 16 + lr;
                    pbuf[((size_t)zIdx * M + row) * D + col] = f2bf(acc[mi][ni][r]);
                }
            }
        }
    }
}

// ---- reduce splits + per-type bias -> f32 out
__global__ void reduce_bias(const unsigned short* __restrict__ pbuf,
                            const int* __restrict__ tnt, const float* __restrict__ root_b,
                            float* __restrict__ out, int M) {
    int idx = blockIdx.x * 256 + threadIdx.x;   // one per 8 outputs
    if (idx >= M * (D / 8)) return;
    int row = idx >> 6;            // D/8 = 64
    int col = (idx & 63) * 8;
    float s[8] = {0.f, 0.f, 0.f, 0.f, 0.f, 0.f, 0.f, 0.f};
#pragma unroll
    for (int sp = 0; sp < SPLITS; ++sp) {
        uint4 v = *reinterpret_cast<const uint4*>(pbuf + ((size_t)sp * M + row) * D + col);
        unsigned u[4] = {v.x, v.y, v.z, v.w};
#pragma unroll
        for (int j = 0; j < 4; ++j) {
            s[2 * j]     += bf2f((unsigned short)(u[j] & 0xFFFF));
            s[2 * j + 1] += bf2f((unsigned short)(u[j] >> 16));
        }
    }
    const float* b = root_b + (size_t)tnt[row] * D + col;
    float4 o0, o1;
    o0.x = s[0] + b[0]; o0.y = s[1] + b[1]; o0.z = s[2] + b[2]; o0.w = s[3] + b[3];
    o1.x = s[4] + b[4]; o1.y = s[5] + b[5]; o1.z = s[6] + b[6]; o1.w = s[7] + b[7];
    float* o = out + (size_t)row * D + col;
    *reinterpret_cast<float4*>(o) = o0;
    *reinterpret_cast<float4*>(o + 4) = o1;
}

extern "C" void kernel_launch(void* const* d_in, const int* in_sizes, int n_in,
                              void* d_out, int out_size, void* d_ws, size_t ws_size,
                              hipStream_t stream) {
    const float* x_src    = (const float*)d_in[0];
    const float* x_target = (const float*)d_in[1];
    const float* relW     = (const float*)d_in[2];
    const float* rootW    = (const float*)d_in[3];
    const float* rootb    = (const float*)d_in[4];
    const int*   esrc     = (const int*)d_in[5];
    const int*   edst     = (const int*)d_in[6];
    const int*   etyp     = (const int*)d_in[7];
    const int*   tnt      = (const int*)d_in[8];
    float* out = (float*)d_out;

    const int E = in_sizes[5];
    const int M = in_sizes[8];          // n_tgt = 10000
    const int NSEG = M * T_ETYPES;      // 80000
    const int NB = (NSEG + 255) / 256;  // 313
    const int MB = (M + 127) / 128;     // 79

    char* ws = (char*)d_ws;
    size_t off = 0;
    unsigned short* Abf = (unsigned short*)(ws + off); off += (size_t)M * K_TOT * 2;       // 122.88 MB
    unsigned short* WbT = (unsigned short*)(ws + off); off += (size_t)D * K_TOT * 2;       // 6.29 MB
    unsigned short* pb  = (unsigned short*)(ws + off); off += (size_t)SPLITS * M * D * 2;  // 40.96 MB
    int* counts    = (int*)(ws + off); off += (size_t)NSEG * 4;
    int* partial   = (int*)(ws + off); off += (size_t)NSEG * 4;
    int* offsets   = (int*)(ws + off); off += (size_t)NSEG * 4;
    int* cursors   = (int*)(ws + off); off += (size_t)NSEG * 4;
    int* blockSums = (int*)(ws + off); off += 512 * 4;
    int* perm      = (int*)(ws + off); off += (size_t)E * 4;

    hipMemsetAsync(counts, 0, (size_t)NSEG * 4, stream);

    convert_weights<<<dim3(K_TOT / 32, D / 32), 256, 0, stream>>>(relW, rootW, WbT);
    hist_kernel<<<(E + 255) / 256, 256, 0, stream>>>(edst, etyp, counts, E);
    scan1<<<NB, 256, 0, stream>>>(counts, partial, blockSums, NSEG);
    scan2<<<1, 512, 0, stream>>>(blockSums, NB);
    scan3<<<NB, 256, 0, stream>>>(partial, blockSums, offsets, cursors, NSEG);
    scatter_kernel<<<(E + 255) / 256, 256, 0, stream>>>(esrc, edst, etyp, cursors, perm, E);
    segmean<<<(NSEG + 3) / 4, 256, 0, stream>>>(x_src, perm, offsets, counts, Abf, NSEG);
    rootfill<<<M, 256, 0, stream>>>(x_target, tnt, Abf, M);
    rgcn_gemm_sk<<<MB * 4 * SPLITS, 256, 0, stream>>>(Abf, WbT, pb, M, MB);
    reduce_bias<<<(M * (D / 8) + 255) / 256, 256, 0, stream>>>(pb, tnt, rootb, out, M);
}